// Round 3
// baseline (118.374 us; speedup 1.0000x reference)
//
#include <hip/hip_runtime.h>
#include <math.h>
#include <stdint.h>

// Problem constants (from reference setup_inputs): B=4, C_in=512, N=4096, OUT=256.
// Key insight: softmax is over a singleton axis -> coefs == 1 everywhere, so
//   out[b,o,0,n] = elu( sum_c W1[o,c] * sum_n x[b,c,0,n] )   (constant over n).
//
// Single-dispatch, barrier-free design. Producer block bi publishes row-sums for
// rows 2bi,2bi+1 as packed (MAGIC<<32 | float_bits) u64 agent-scope stores at
// independent addresses (no central counter, no RMW contention). Consumer thread
// t of block (b,o) polls exactly the two words its GEMV slice needs -- the poll
// loads ARE the gemv loads.
//
// Round-2 lesson: s_sleep(2) polling (~128 cyc cadence) generated ~2000 agent-
// scope loads/cycle chip-wide during phase 1 -- self-inflicted L2/L3 congestion.
// This version polls at ~4096-cycle cadence (s_sleep(64), ~1.7 us), cutting poll
// traffic ~30x to a negligible level while phase 1 (~6 us) completes.
#define NN    4096
#define CIN   512
#define COUT  256
#define BB    4
#define MAGIC 0x7F3A9C51u   // 4 distinct bytes: no repeated-byte poison collides

typedef unsigned long long u64;

__device__ __forceinline__ float row_sum_direct(const float* __restrict__ x, int row) {
    // Fallback only (bounded-spin timeout): serial per-thread row sum.
    const float4* p = (const float4*)(x + (size_t)row * NN);
    float s = 0.f;
    for (int i = 0; i < NN / 4; ++i) {
        float4 v = p[i];
        s += (v.x + v.y) + (v.z + v.w);
    }
    return s;
}

__device__ __forceinline__ float wait_word(const u64* __restrict__ sig, int idx,
                                           const float* __restrict__ x) {
    u64 q;
    int spins = 0;
    for (;;) {
        q = __hip_atomic_load(&sig[idx], __ATOMIC_RELAXED, __HIP_MEMORY_SCOPE_AGENT);
        if ((unsigned)(q >> 32) == MAGIC) break;
        if (++spins > 4096) {            // ~7 ms worth of 1.7us sleeps: unreachable unless broken
            union { float f; unsigned u; } c;
            c.f = row_sum_direct(x, idx);
            return c.f;
        }
        __builtin_amdgcn_s_sleep(64);    // ~4096 cycles (~1.7 us) between polls
    }
    union { float f; unsigned u; } c;
    c.u = (unsigned)q;
    return c.f;
}

__global__ __launch_bounds__(256) void fused_sig_kernel(const float* __restrict__ x,
                                                        const float* __restrict__ W1,
                                                        u64* __restrict__ sig,
                                                        float* __restrict__ out) {
    const int bi = blockIdx.x;                        // 0..1023
    const int t  = threadIdx.x;                       // 0..255
    const int wave = t >> 6, lane = t & 63;
    __shared__ float w0[4], w1[4], ws2[4];

    // ---- Phase 1 (produce): row sums for rows 2bi, 2bi+1 (32 KB contiguous) ----
    const float4* p0 = (const float4*)(x + (size_t)(2 * bi) * NN);
    const float4* p1 = p0 + (NN / 4);
    float s0 = 0.f, s1 = 0.f;
    #pragma unroll
    for (int i = 0; i < 4; ++i) {
        float4 a = p0[t + i * 256];
        float4 b = p1[t + i * 256];
        s0 += (a.x + a.y) + (a.z + a.w);
        s1 += (b.x + b.y) + (b.z + b.w);
    }
    #pragma unroll
    for (int off = 32; off; off >>= 1) {
        s0 += __shfl_down(s0, off, 64);
        s1 += __shfl_down(s1, off, 64);
    }
    if (lane == 0) { w0[wave] = s0; w1[wave] = s1; }
    __syncthreads();
    if (t == 0) {
        union { float f; unsigned u; } c0, c1;
        c0.f = (w0[0] + w0[1]) + (w0[2] + w0[3]);
        c1.f = (w1[0] + w1[1]) + (w1[2] + w1[3]);
        __hip_atomic_store(&sig[2 * bi],     ((u64)MAGIC << 32) | (u64)c0.u,
                           __ATOMIC_RELAXED, __HIP_MEMORY_SCOPE_AGENT);
        __hip_atomic_store(&sig[2 * bi + 1], ((u64)MAGIC << 32) | (u64)c1.u,
                           __ATOMIC_RELAXED, __HIP_MEMORY_SCOPE_AGENT);
    }

    // ---- Phase 2 (consume): block bi == (b, o); dot(W1[o,:], xs[b,:]) + elu + bcast ----
    const int b = bi >> 8;                            // COUT == 256
    const int o = bi & 255;
    const int base = b * CIN;
    const float* w = W1 + (size_t)o * CIN;
    const float w_a = w[t];                           // issue W1 loads before polling
    const float w_b = w[t + 256];

    const float f1 = wait_word(sig, base + t,       x);
    const float f2 = wait_word(sig, base + 256 + t, x);

    float s = w_a * f1 + w_b * f2;
    #pragma unroll
    for (int off = 32; off; off >>= 1) s += __shfl_down(s, off, 64);
    if (lane == 0) ws2[wave] = s;
    __syncthreads();
    const float S = (ws2[0] + ws2[1]) + (ws2[2] + ws2[3]);
    const float e = (S > 0.f) ? S : (expf(S) - 1.f);
    float4 val = make_float4(e, e, e, e);
    float4* po = (float4*)(out + (size_t)bi * NN);
    #pragma unroll
    for (int i = 0; i < 4; ++i) po[t + i * 256] = val;
}

extern "C" void kernel_launch(void* const* d_in, const int* in_sizes, int n_in,
                              void* d_out, int out_size, void* d_ws, size_t ws_size,
                              hipStream_t stream) {
    const float* x  = (const float*)d_in[0];   // [B, CIN, 1, N]
    const float* W1 = (const float*)d_in[1];   // [COUT, CIN]
    // d_in[2] (w2) and d_in[3] (bias_mat) are dead: softmax over singleton axis.
    float* out = (float*)d_out;                // [B, COUT, 1, N]
    u64* sig   = (u64*)d_ws;                   // 2048 packed (flag|value) words = 16 KB

    fused_sig_kernel<<<BB * COUT, 256, 0, stream>>>(x, W1, sig, out);
}

// Round 4
// 114.049 us; speedup vs baseline: 1.0379x; 1.0379x over previous
//
#include <hip/hip_runtime.h>
#include <math.h>

// Problem constants (from reference setup_inputs): B=4, C_in=512, N=4096, OUT=256.
// Key insight: softmax is over a singleton axis -> coefs == 1 everywhere, so
//   out[b,o,0,n] = elu( sum_c W1[o,c] * sum_n x[b,c,0,n] )   (constant over n).
//
// Session conclusion (R0-R3): the two-kernel back-to-back dispatch is the
// measured optimum. Fusion alternatives are structurally worse on MI355X:
//   - cg::grid_sync: ~70us centralized barrier across 8 non-coherent XCD L2s (R1)
//   - value-signaling + poll: s_sleep wake-up quantization after last producer,
//     costs ~5us over plain dispatch, independent of poll cadence (R2/R3)
// Remaining measured time (~83us) is harness poison fills (256 MiB at 80-83% of
// HBM peak -- themselves at the memory roofline), not kernel-addressable.

#define NN   4096
#define CIN  512
#define COUT 256
#define BB   4

// One block per (b,c) row: reduce 4096 floats -> xs[b*CIN+c].
__global__ __launch_bounds__(256) void row_sum_kernel(const float* __restrict__ x,
                                                      float* __restrict__ xs) {
    const int row = blockIdx.x;                       // 0 .. B*CIN-1
    const float4* p = (const float4*)(x + (size_t)row * NN);
    const int t = threadIdx.x;                        // 0..255
    float s = 0.f;
    // 4096 floats = 1024 float4; 256 threads * 4 each, coalesced.
    #pragma unroll
    for (int i = 0; i < 4; ++i) {
        float4 v = p[t + i * 256];
        s += (v.x + v.y) + (v.z + v.w);
    }
    // wave64 shuffle reduce, then LDS across the 4 waves
    #pragma unroll
    for (int off = 32; off; off >>= 1) s += __shfl_down(s, off, 64);
    __shared__ float wsum[4];
    const int wave = t >> 6, lane = t & 63;
    if (lane == 0) wsum[wave] = s;
    __syncthreads();
    if (t == 0) xs[row] = (wsum[0] + wsum[1]) + (wsum[2] + wsum[3]);
}

// One block per (b,o): dot(W1[o,:], xs[b,:]) over 512, elu, broadcast 4096 writes.
__global__ __launch_bounds__(256) void gemv_elu_bcast_kernel(const float* __restrict__ W1,
                                                             const float* __restrict__ xs,
                                                             float* __restrict__ out) {
    const int blk = blockIdx.x;                       // b*COUT + o
    const int b = blk >> 8;                           // COUT == 256
    const int o = blk & 255;
    const int t = threadIdx.x;
    const float* w = W1 + (size_t)o * CIN;
    const float* v = xs + (size_t)b * CIN;
    float s = w[t] * v[t] + w[t + 256] * v[t + 256];
    #pragma unroll
    for (int off = 32; off; off >>= 1) s += __shfl_down(s, off, 64);
    __shared__ float wsum[4];
    const int wave = t >> 6, lane = t & 63;
    if (lane == 0) wsum[wave] = s;
    __syncthreads();
    const float S = (wsum[0] + wsum[1]) + (wsum[2] + wsum[3]);
    const float e = (S > 0.f) ? S : (expf(S) - 1.f);
    float4 val = make_float4(e, e, e, e);
    float4* po = (float4*)(out + (size_t)blk * NN);
    #pragma unroll
    for (int i = 0; i < 4; ++i) po[t + i * 256] = val;
}

extern "C" void kernel_launch(void* const* d_in, const int* in_sizes, int n_in,
                              void* d_out, int out_size, void* d_ws, size_t ws_size,
                              hipStream_t stream) {
    const float* x  = (const float*)d_in[0];   // [B, CIN, 1, N]
    const float* W1 = (const float*)d_in[1];   // [COUT, CIN]
    // d_in[2] (w2) and d_in[3] (bias_mat) are dead: softmax over singleton axis.
    float* out = (float*)d_out;                // [B, COUT, 1, N]
    float* xs  = (float*)d_ws;                 // B*CIN floats = 8 KB scratch

    row_sum_kernel<<<BB * CIN, 256, 0, stream>>>(x, xs);
    gemv_elu_bcast_kernel<<<BB * COUT, 256, 0, stream>>>(W1, xs, out);
}